// Round 1
// baseline (244.480 us; speedup 1.0000x reference)
//
#include <hip/hip_runtime.h>

typedef short bf16x8 __attribute__((ext_vector_type(8)));
typedef float f32x4 __attribute__((ext_vector_type(4)));
typedef unsigned short us8 __attribute__((ext_vector_type(8)));

__device__ __forceinline__ unsigned short f2bf(float f) {
    unsigned int u = __float_as_uint(f);
    u += 0x7fffu + ((u >> 16) & 1u);   // round-to-nearest-even
    return (unsigned short)(u >> 16);
}

// ---- transpose + cast fp32 -> bf16 bits: out[Cc][R] = cast(in[R][Cc]) ----
__global__ __launch_bounds__(256) void transpose_cast_kernel(
    const float* __restrict__ in, unsigned short* __restrict__ out, int R, int Cc) {
    __shared__ alignas(16) unsigned short sT[64][65];
    const int r0 = blockIdx.x * 64, c0 = blockIdx.y * 64;
    const int t = threadIdx.x;
#pragma unroll
    for (int p = 0; p < 16; ++p) {
        int flat = p * 256 + t;
        int r = flat >> 6, c = flat & 63;
        sT[c][r] = f2bf(in[(size_t)(r0 + r) * Cc + (c0 + c)]);
    }
    __syncthreads();
#pragma unroll
    for (int p = 0; p < 16; ++p) {
        int flat = p * 256 + t;
        int c = flat >> 6, r = flat & 63;
        out[(size_t)(c0 + c) * R + (r0 + r)] = sT[c][r];
    }
}

// ---- sum 4 fp32 partial slabs, cast to bf16 ----
__global__ __launch_bounds__(256) void fuse_sum_cast_kernel(
    const float* __restrict__ p, unsigned short* __restrict__ o, long n, long stride) {
    long i = ((long)blockIdx.x * 256 + threadIdx.x) * 4;
    long gs = (long)gridDim.x * 1024;
    for (; i < n; i += gs) {
        float4 a = *(const float4*)&p[i];
        float4 b = *(const float4*)&p[stride + i];
        float4 c = *(const float4*)&p[2 * stride + i];
        float4 d = *(const float4*)&p[3 * stride + i];
        ushort4 r = make_ushort4(f2bf(a.x + b.x + c.x + d.x),
                                 f2bf(a.y + b.y + c.y + d.y),
                                 f2bf(a.z + b.z + c.z + d.z),
                                 f2bf(a.w + b.w + c.w + d.w));
        *(ushort4*)&o[i] = r;
    }
}

// ---- MFMA GEMM: C[M][N] (+= K-split partials) = A[M][K] @ (BT[N][K])^T ----
// A: fp32 (converted during staging) if AF32, else bf16 bits.
// BM=64, BN=256 (full N), BK=64; 4 waves, wave tile 64x64 (acc 4x4 of 16x16x32).
// K-split via gridDim.z -> partial slab z at C + z*M*N (fp32).
// TOUT: write bf16 transposed C[N][M] (with optional relu) -- used for h^T.
template<bool AF32, bool RELU, bool TOUT, typename OutT>
__global__ __launch_bounds__(256) void gemm_kernel(
    const void* __restrict__ Aptr, const unsigned short* __restrict__ BT,
    OutT* __restrict__ C, int M, int N, int K) {
    constexpr int BM = 64, BN = 256, BK = 64, LDB_ = 72;  // 72: pad rows to 144 B
    __shared__ alignas(16) unsigned short sA[BM * LDB_];
    __shared__ alignas(16) unsigned short sB[BN * LDB_];
    const int t = threadIdx.x;
    const int w = t >> 6, l = t & 63;
    const int m0 = blockIdx.x * BM;
    const int klen = K / gridDim.z;
    const int kbeg = blockIdx.z * klen;
    OutT* Cp = C + (size_t)blockIdx.z * M * N;

    f32x4 acc[4][4] = {};

    for (int k0 = kbeg; k0 < kbeg + klen; k0 += BK) {
        if constexpr (AF32) {
            const float* A32 = (const float*)Aptr;
#pragma unroll
            for (int p = 0; p < 4; ++p) {
                int flat = p * 256 + t;               // 1024 float4 chunks
                int row = flat >> 4, c4 = flat & 15;  // 16 float4 per row
                float4 v = *(const float4*)&A32[(size_t)(m0 + row) * K + k0 + c4 * 4];
                ushort4 o = make_ushort4(f2bf(v.x), f2bf(v.y), f2bf(v.z), f2bf(v.w));
                *(ushort4*)&sA[row * LDB_ + c4 * 4] = o;
            }
        } else {
            const unsigned short* A16 = (const unsigned short*)Aptr;
#pragma unroll
            for (int p = 0; p < 2; ++p) {
                int flat = p * 256 + t;               // 512 16B chunks
                int row = flat >> 3, c8 = flat & 7;   // 8 chunks per row
                us8 v = *(const us8*)&A16[(size_t)(m0 + row) * K + k0 + c8 * 8];
                *(us8*)&sA[row * LDB_ + c8 * 8] = v;
            }
        }
#pragma unroll
        for (int p = 0; p < 8; ++p) {
            int flat = p * 256 + t;                   // 2048 16B chunks
            int row = flat >> 3, c8 = flat & 7;
            us8 v = *(const us8*)&BT[(size_t)row * K + k0 + c8 * 8];
            *(us8*)&sB[row * LDB_ + c8 * 8] = v;
        }
        __syncthreads();
#pragma unroll
        for (int kk = 0; kk < BK; kk += 32) {
            bf16x8 av[4], bv[4];
#pragma unroll
            for (int m = 0; m < 4; ++m)
                av[m] = *(const bf16x8*)&sA[(m * 16 + (l & 15)) * LDB_ + kk + (l >> 4) * 8];
#pragma unroll
            for (int n = 0; n < 4; ++n)
                bv[n] = *(const bf16x8*)&sB[(w * 64 + n * 16 + (l & 15)) * LDB_ + kk + (l >> 4) * 8];
#pragma unroll
            for (int m = 0; m < 4; ++m)
#pragma unroll
                for (int n = 0; n < 4; ++n)
                    acc[m][n] = __builtin_amdgcn_mfma_f32_16x16x32_bf16(av[m], bv[n], acc[m][n], 0, 0, 0);
        }
        __syncthreads();
    }

#pragma unroll
    for (int m = 0; m < 4; ++m) {
#pragma unroll
        for (int n = 0; n < 4; ++n) {
            const int col = w * 64 + n * 16 + (l & 15);
            const int rb = m0 + m * 16 + ((l >> 4) << 2);
            float v0 = acc[m][n][0], v1 = acc[m][n][1], v2 = acc[m][n][2], v3 = acc[m][n][3];
            if (RELU) {
                v0 = fmaxf(v0, 0.f); v1 = fmaxf(v1, 0.f);
                v2 = fmaxf(v2, 0.f); v3 = fmaxf(v3, 0.f);
            }
            if constexpr (TOUT) {
                ushort4 o = make_ushort4(f2bf(v0), f2bf(v1), f2bf(v2), f2bf(v3));
                *(ushort4*)((unsigned short*)Cp + (size_t)col * M + rb) = o;
            } else {
                Cp[(size_t)(rb + 0) * N + col] = (OutT)v0;
                Cp[(size_t)(rb + 1) * N + col] = (OutT)v1;
                Cp[(size_t)(rb + 2) * N + col] = (OutT)v2;
                Cp[(size_t)(rb + 3) * N + col] = (OutT)v3;
            }
        }
    }
}

// ---- head: o = (sum_z t2p[z]) @ W2 ; out = log_softmax(o, axis=1) ----
// one wave per row, lane = class (64 classes). W2 (256x64 fp32) staged in LDS.
__global__ __launch_bounds__(256) void head_kernel(
    const float* __restrict__ t2p, const float* __restrict__ W2,
    float* __restrict__ out, int M) {
    __shared__ alignas(16) float sW2[256 * 64];  // 64 KB
    const int t = threadIdx.x;
#pragma unroll
    for (int p = 0; p < 16; ++p)
        ((float4*)sW2)[p * 256 + t] = ((const float4*)W2)[p * 256 + t];
    __syncthreads();
    const int w = t >> 6, l = t & 63;
    const size_t stride = (size_t)M * 256;
#pragma unroll
    for (int rr = 0; rr < 4; ++rr) {
        int i = blockIdx.x * 16 + w * 4 + rr;
        const float* r0 = &t2p[(size_t)i * 256 + l * 4];
        float4 a = *(const float4*)&r0[0];
        float4 b = *(const float4*)&r0[stride];
        float4 c = *(const float4*)&r0[2 * stride];
        float4 d = *(const float4*)&r0[3 * stride];
        float rx = a.x + b.x + c.x + d.x;
        float ry = a.y + b.y + c.y + d.y;
        float rz = a.z + b.z + c.z + d.z;
        float rw = a.w + b.w + c.w + d.w;
        float acc = 0.f;
#pragma unroll 8
        for (int jb = 0; jb < 64; ++jb) {
            float a0 = __shfl(rx, jb), a1 = __shfl(ry, jb);
            float a2 = __shfl(rz, jb), a3 = __shfl(rw, jb);
            const float* wp = &sW2[jb * 256];
            acc = fmaf(a0, wp[l], acc);
            acc = fmaf(a1, wp[64 + l], acc);
            acc = fmaf(a2, wp[128 + l], acc);
            acc = fmaf(a3, wp[192 + l], acc);
        }
        float mx = acc;
#pragma unroll
        for (int off = 32; off; off >>= 1) mx = fmaxf(mx, __shfl_xor(mx, off));
        float d0 = acc - mx;
        float e = __expf(d0);
#pragma unroll
        for (int off = 32; off; off >>= 1) e += __shfl_xor(e, off);
        out[(size_t)i * 64 + l] = d0 - __logf(e);
    }
}

extern "C" void kernel_launch(void* const* d_in, const int* in_sizes, int n_in,
                              void* d_out, int out_size, void* d_ws, size_t ws_size,
                              hipStream_t stream) {
    const float* adj = (const float*)d_in[0];
    const float* x   = (const float*)d_in[1];
    const float* W1  = (const float*)d_in[2];
    const float* W2  = (const float*)d_in[3];
    float* out = (float*)d_out;

    const int M = 8192, K = 8192, F = 256;
    char* ws = (char*)d_ws;
    // ws layout (44.1 MB total):
    float*          pbuf = (float*)ws;                        // 4 slabs * 8 MB (t1 partials, then t2 partials)
    unsigned short* xT   = (unsigned short*)(ws + 33554432);  // 4 MB  : x^T  bf16 [256][8192]
    unsigned short* W1T  = (unsigned short*)(ws + 37748736);  // 128 KB: W1^T bf16 [256][256]
    unsigned short* t1B  = (unsigned short*)(ws + 37879808);  // 4 MB  : t1   bf16 [8192][256]
    unsigned short* hT   = (unsigned short*)(ws + 42074112);  // 4 MB  : h^T  bf16 [256][8192]

    transpose_cast_kernel<<<dim3(M / 64, F / 64), 256, 0, stream>>>(x, xT, M, F);
    transpose_cast_kernel<<<dim3(F / 64, F / 64), 256, 0, stream>>>(W1, W1T, F, F);
    // t1 partials = adj @ x  (K-split 4)
    gemm_kernel<true, false, false, float>
        <<<dim3(M / 64, 1, 4), 256, 0, stream>>>(adj, xT, pbuf, M, F, K);
    fuse_sum_cast_kernel<<<dim3(2048), 256, 0, stream>>>(pbuf, t1B, (long)M * F, (long)M * F);
    // h^T = relu(t1 @ W1)^T   (bf16, transposed write)
    gemm_kernel<false, true, true, unsigned short>
        <<<dim3(M / 64, 1, 1), 256, 0, stream>>>(t1B, W1T, hT, M, F, F);
    // t2 partials = adj @ h  (K-split 4)
    gemm_kernel<true, false, false, float>
        <<<dim3(M / 64, 1, 4), 256, 0, stream>>>(adj, hT, pbuf, M, F, K);
    head_kernel<<<dim3(M / 16), 256, 0, stream>>>(pbuf, W2, out, M);
}

// Round 2
// 216.323 us; speedup vs baseline: 1.1302x; 1.1302x over previous
//
#include <hip/hip_runtime.h>

typedef short bf16x8 __attribute__((ext_vector_type(8)));
typedef float f32x4 __attribute__((ext_vector_type(4)));
typedef unsigned short us8 __attribute__((ext_vector_type(8)));

__device__ __forceinline__ unsigned short f2bf(float f) {
    unsigned int u = __float_as_uint(f);
    u += 0x7fffu + ((u >> 16) & 1u);   // round-to-nearest-even
    return (unsigned short)(u >> 16);
}

// ---- transpose + cast fp32 -> bf16 bits: out[Cc][R] = cast(in[R][Cc]) ----
__global__ __launch_bounds__(256) void transpose_cast_kernel(
    const float* __restrict__ in, unsigned short* __restrict__ out, int R, int Cc) {
    __shared__ alignas(16) unsigned short sT[64][65];
    const int r0 = blockIdx.x * 64, c0 = blockIdx.y * 64;
    const int t = threadIdx.x;
#pragma unroll
    for (int p = 0; p < 16; ++p) {
        int flat = p * 256 + t;
        int r = flat >> 6, c = flat & 63;
        sT[c][r] = f2bf(in[(size_t)(r0 + r) * Cc + (c0 + c)]);
    }
    __syncthreads();
#pragma unroll
    for (int p = 0; p < 16; ++p) {
        int flat = p * 256 + t;
        int c = flat >> 6, r = flat & 63;
        out[(size_t)(c0 + c) * R + (r0 + r)] = sT[c][r];
    }
}

// ---- MFMA GEMM: C[M][N] = A[M][K] @ (BT[N][K])^T, K-split via gridDim.z ----
// BM=64, BK=64. Wave grid WM x WN (4 waves). Templated BN (full N per block).
// AMODE 1: A fp32, convert to bf16 during staging.
// AMODE 2: A = relu(sum of 4 fp32 slabs, stride aslab), convert during staging.
// TOUT: write bf16 transposed C[N][M] (for producing B-operands of later GEMMs).
template<int BN, int WM, int WN, int AMODE, bool TOUT, typename OutT>
__global__ __launch_bounds__(256) void gemm_kernel(
    const void* __restrict__ Aptr, const unsigned short* __restrict__ BT,
    OutT* __restrict__ C, int M, int N, int K, long aslab) {
    constexpr int BM = 64, BK = 64, LDW = 72;  // 72: pad rows to 144 B (bank-safe)
    constexpr int MF = BM / WM / 16;           // m-frags per wave
    constexpr int NF = BN / WN / 16;           // n-frags per wave
    __shared__ alignas(16) unsigned short sA[BM * LDW];
    __shared__ alignas(16) unsigned short sB[BN * LDW];
    const int t = threadIdx.x;
    const int w = t >> 6, l = t & 63;
    const int wr = w / WN, wc = w % WN;
    const int m0 = blockIdx.x * BM;
    const int klen = K / gridDim.z;
    const int kbeg = blockIdx.z * klen;
    OutT* Cp = C + (size_t)blockIdx.z * M * N;

    f32x4 acc[MF][NF] = {};

    for (int k0 = kbeg; k0 < kbeg + klen; k0 += BK) {
        const float* A32 = (const float*)Aptr;
#pragma unroll
        for (int p = 0; p < 4; ++p) {
            int flat = p * 256 + t;               // 1024 float4 chunks (64x64 fp32)
            int row = flat >> 4, c4 = flat & 15;  // 16 float4 per row
            size_t base = (size_t)(m0 + row) * K + k0 + c4 * 4;
            float4 v = *(const float4*)&A32[base];
            if constexpr (AMODE == 2) {
                float4 b = *(const float4*)&A32[aslab + base];
                float4 c = *(const float4*)&A32[2 * aslab + base];
                float4 d = *(const float4*)&A32[3 * aslab + base];
                v.x = fmaxf(v.x + b.x + c.x + d.x, 0.f);
                v.y = fmaxf(v.y + b.y + c.y + d.y, 0.f);
                v.z = fmaxf(v.z + b.z + c.z + d.z, 0.f);
                v.w = fmaxf(v.w + b.w + c.w + d.w, 0.f);
            }
            ushort4 o = make_ushort4(f2bf(v.x), f2bf(v.y), f2bf(v.z), f2bf(v.w));
            *(ushort4*)&sA[row * LDW + c4 * 4] = o;
        }
#pragma unroll
        for (int p = 0; p < BN * 8 / 256; ++p) {
            int flat = p * 256 + t;               // BN*8 16B chunks
            int row = flat >> 3, c8 = flat & 7;
            us8 v = *(const us8*)&BT[(size_t)row * K + k0 + c8 * 8];
            *(us8*)&sB[row * LDW + c8 * 8] = v;
        }
        __syncthreads();
#pragma unroll
        for (int kk = 0; kk < BK; kk += 32) {
            bf16x8 av[MF], bv[NF];
#pragma unroll
            for (int m = 0; m < MF; ++m)
                av[m] = *(const bf16x8*)&sA[(wr * (BM / WM) + m * 16 + (l & 15)) * LDW + kk + (l >> 4) * 8];
#pragma unroll
            for (int n = 0; n < NF; ++n)
                bv[n] = *(const bf16x8*)&sB[(wc * (BN / WN) + n * 16 + (l & 15)) * LDW + kk + (l >> 4) * 8];
#pragma unroll
            for (int m = 0; m < MF; ++m)
#pragma unroll
                for (int n = 0; n < NF; ++n)
                    acc[m][n] = __builtin_amdgcn_mfma_f32_16x16x32_bf16(av[m], bv[n], acc[m][n], 0, 0, 0);
        }
        __syncthreads();
    }

#pragma unroll
    for (int m = 0; m < MF; ++m) {
#pragma unroll
        for (int n = 0; n < NF; ++n) {
            const int col = wc * (BN / WN) + n * 16 + (l & 15);
            const int rb = m0 + wr * (BM / WM) + m * 16 + ((l >> 4) << 2);
            float v0 = acc[m][n][0], v1 = acc[m][n][1], v2 = acc[m][n][2], v3 = acc[m][n][3];
            if constexpr (TOUT) {
                ushort4 o = make_ushort4(f2bf(v0), f2bf(v1), f2bf(v2), f2bf(v3));
                *(ushort4*)((unsigned short*)Cp + (size_t)col * M + rb) = o;
            } else {
                Cp[(size_t)(rb + 0) * N + col] = (OutT)v0;
                Cp[(size_t)(rb + 1) * N + col] = (OutT)v1;
                Cp[(size_t)(rb + 2) * N + col] = (OutT)v2;
                Cp[(size_t)(rb + 3) * N + col] = (OutT)v3;
            }
        }
    }
}

// ---- head: reduce 4 fp32 partial slabs of o[8192][64], then log_softmax rows ----
// one wave per row, lane = class.
__global__ __launch_bounds__(256) void head2_kernel(
    const float* __restrict__ p, float* __restrict__ out, int M) {
    const int t = threadIdx.x, w = t >> 6, l = t & 63;
    const size_t stride = (size_t)M * 64;
#pragma unroll
    for (int rr = 0; rr < 4; ++rr) {
        int i = blockIdx.x * 16 + w * 4 + rr;
        size_t off = (size_t)i * 64 + l;
        float v = p[off] + p[stride + off] + p[2 * stride + off] + p[3 * stride + off];
        float mx = v;
#pragma unroll
        for (int o = 32; o; o >>= 1) mx = fmaxf(mx, __shfl_xor(mx, o));
        float d0 = v - mx;
        float e = __expf(d0);
#pragma unroll
        for (int o = 32; o; o >>= 1) e += __shfl_xor(e, o);
        out[off] = d0 - __logf(e);
    }
}

extern "C" void kernel_launch(void* const* d_in, const int* in_sizes, int n_in,
                              void* d_out, int out_size, void* d_ws, size_t ws_size,
                              hipStream_t stream) {
    const float* adj = (const float*)d_in[0];
    const float* x   = (const float*)d_in[1];
    const float* W1  = (const float*)d_in[2];
    const float* W2  = (const float*)d_in[3];
    float* out = (float*)d_out;

    const int M = 8192, K = 8192;
    char* ws = (char*)d_ws;
    // ws layout (~45.3 MB; ws_size ~1 GB):
    float*          pbuf1 = (float*)ws;                        // 32 MB: 4 slabs t1 partials [8192][256]
    float*          pbuf2 = (float*)(ws + 33554432);           //  8 MB: 4 slabs o partials  [8192][64]
    unsigned short* zT    = (unsigned short*)(ws + 41943040);  //  4 MB: z^T  bf16 [256][8192]
    unsigned short* hwT   = (unsigned short*)(ws + 46137344);  //  1 MB: hw^T bf16 [64][8192]
    unsigned short* W1T   = (unsigned short*)(ws + 47185920);  // 128 KB: W1^T bf16 [256][256]
    unsigned short* W2T   = (unsigned short*)(ws + 47317000 - 8);  // 32 KB: W2^T bf16 [64][256]

    transpose_cast_kernel<<<dim3(4, 4), 256, 0, stream>>>(W1, W1T, 256, 256);
    transpose_cast_kernel<<<dim3(4, 1), 256, 0, stream>>>(W2, W2T, 256, 64);
    // z^T = (x @ W1)^T, bf16
    gemm_kernel<256, 1, 4, 1, true, unsigned short>
        <<<dim3(M / 64, 1, 1), 256, 0, stream>>>(x, W1T, zT, M, 256, 256, 0);
    // t1 partials = adj @ z  (K-split 4)
    gemm_kernel<256, 1, 4, 1, false, float>
        <<<dim3(M / 64, 1, 4), 256, 0, stream>>>(adj, zT, pbuf1, M, 256, K, 0);
    // hw^T = (relu(sum t1 partials) @ W2)^T, bf16
    gemm_kernel<64, 2, 2, 2, true, unsigned short>
        <<<dim3(M / 64, 1, 1), 256, 0, stream>>>(pbuf1, W2T, hwT, M, 64, 256, (long)M * 256);
    // o partials = adj @ hw  (K-split 4)
    gemm_kernel<64, 2, 2, 1, false, float>
        <<<dim3(M / 64, 1, 4), 256, 0, stream>>>(adj, hwT, pbuf2, M, 64, K, 0);
    head2_kernel<<<dim3(M / 16), 256, 0, stream>>>(pbuf2, out, M);
}

// Round 3
// 167.950 us; speedup vs baseline: 1.4557x; 1.2880x over previous
//
#include <hip/hip_runtime.h>

typedef short bf16x8 __attribute__((ext_vector_type(8)));
typedef float f32x4 __attribute__((ext_vector_type(4)));
typedef unsigned short us8 __attribute__((ext_vector_type(8)));

__device__ __forceinline__ unsigned short f2bf(float f) {
    unsigned int u = __float_as_uint(f);
    u += 0x7fffu + ((u >> 16) & 1u);   // round-to-nearest-even
    return (unsigned short)(u >> 16);
}

// ---- transpose + cast fp32 -> bf16 bits: out[Cc][R] = cast(in[R][Cc]) ----
__global__ __launch_bounds__(256) void transpose_cast_kernel(
    const float* __restrict__ in, unsigned short* __restrict__ out, int R, int Cc) {
    __shared__ alignas(16) unsigned short sT[64][65];
    const int r0 = blockIdx.x * 64, c0 = blockIdx.y * 64;
    const int t = threadIdx.x;
#pragma unroll
    for (int p = 0; p < 16; ++p) {
        int flat = p * 256 + t;
        int r = flat >> 6, c = flat & 63;
        sT[c][r] = f2bf(in[(size_t)(r0 + r) * Cc + (c0 + c)]);
    }
    __syncthreads();
#pragma unroll
    for (int p = 0; p < 16; ++p) {
        int flat = p * 256 + t;
        int c = flat >> 6, r = flat & 63;
        out[(size_t)(c0 + c) * R + (r0 + r)] = sT[c][r];
    }
}

// ---- small MFMA GEMM (BM=64, 4 waves): C[M][N] = A[M][K] @ (BT[N][K])^T ----
// AMODE 1: A fp32 -> bf16 during staging.
// AMODE 2: A = relu(sum of 4 fp32 slabs, stride aslab) -> bf16 during staging.
// TOUT: write bf16 transposed C[N][M].
template<int BN, int WM, int WN, int AMODE, bool TOUT, typename OutT>
__global__ __launch_bounds__(256) void gemm_kernel(
    const void* __restrict__ Aptr, const unsigned short* __restrict__ BT,
    OutT* __restrict__ C, int M, int N, int K, long aslab) {
    constexpr int BM = 64, BK = 64, LDW = 72;
    constexpr int MF = BM / WM / 16;
    constexpr int NF = BN / WN / 16;
    __shared__ alignas(16) unsigned short sA[BM * LDW];
    __shared__ alignas(16) unsigned short sB[BN * LDW];
    const int t = threadIdx.x;
    const int w = t >> 6, l = t & 63;
    const int wr = w / WN, wc = w % WN;
    const int m0 = blockIdx.x * BM;
    const int klen = K / gridDim.z;
    const int kbeg = blockIdx.z * klen;
    OutT* Cp = C + (size_t)blockIdx.z * M * N;

    f32x4 acc[MF][NF] = {};

    for (int k0 = kbeg; k0 < kbeg + klen; k0 += BK) {
        const float* A32 = (const float*)Aptr;
#pragma unroll
        for (int p = 0; p < 4; ++p) {
            int flat = p * 256 + t;
            int row = flat >> 4, c4 = flat & 15;
            size_t base = (size_t)(m0 + row) * K + k0 + c4 * 4;
            float4 v = *(const float4*)&A32[base];
            if constexpr (AMODE == 2) {
                float4 b = *(const float4*)&A32[aslab + base];
                float4 c = *(const float4*)&A32[2 * aslab + base];
                float4 d = *(const float4*)&A32[3 * aslab + base];
                v.x = fmaxf(v.x + b.x + c.x + d.x, 0.f);
                v.y = fmaxf(v.y + b.y + c.y + d.y, 0.f);
                v.z = fmaxf(v.z + b.z + c.z + d.z, 0.f);
                v.w = fmaxf(v.w + b.w + c.w + d.w, 0.f);
            }
            ushort4 o = make_ushort4(f2bf(v.x), f2bf(v.y), f2bf(v.z), f2bf(v.w));
            *(ushort4*)&sA[row * LDW + c4 * 4] = o;
        }
#pragma unroll
        for (int p = 0; p < BN * 8 / 256; ++p) {
            int flat = p * 256 + t;
            int row = flat >> 3, c8 = flat & 7;
            us8 v = *(const us8*)&BT[(size_t)row * K + k0 + c8 * 8];
            *(us8*)&sB[row * LDW + c8 * 8] = v;
        }
        __syncthreads();
#pragma unroll
        for (int kk = 0; kk < BK; kk += 32) {
            bf16x8 av[MF], bv[NF];
#pragma unroll
            for (int m = 0; m < MF; ++m)
                av[m] = *(const bf16x8*)&sA[(wr * (BM / WM) + m * 16 + (l & 15)) * LDW + kk + (l >> 4) * 8];
#pragma unroll
            for (int n = 0; n < NF; ++n)
                bv[n] = *(const bf16x8*)&sB[(wc * (BN / WN) + n * 16 + (l & 15)) * LDW + kk + (l >> 4) * 8];
#pragma unroll
            for (int m = 0; m < MF; ++m)
#pragma unroll
                for (int n = 0; n < NF; ++n)
                    acc[m][n] = __builtin_amdgcn_mfma_f32_16x16x32_bf16(av[m], bv[n], acc[m][n], 0, 0, 0);
        }
        __syncthreads();
    }

#pragma unroll
    for (int m = 0; m < MF; ++m) {
#pragma unroll
        for (int n = 0; n < NF; ++n) {
            const int col = wc * (BN / WN) + n * 16 + (l & 15);
            const int rb = m0 + wr * (BM / WM) + m * 16 + ((l >> 4) << 2);
            float v0 = acc[m][n][0], v1 = acc[m][n][1], v2 = acc[m][n][2], v3 = acc[m][n][3];
            if constexpr (TOUT) {
                ushort4 o = make_ushort4(f2bf(v0), f2bf(v1), f2bf(v2), f2bf(v3));
                *(ushort4*)((unsigned short*)Cp + (size_t)col * M + rb) = o;
            } else {
                Cp[(size_t)(rb + 0) * N + col] = (OutT)v0;
                Cp[(size_t)(rb + 1) * N + col] = (OutT)v1;
                Cp[(size_t)(rb + 2) * N + col] = (OutT)v2;
                Cp[(size_t)(rb + 3) * N + col] = (OutT)v3;
            }
        }
    }
}

// ---- big adj-streaming GEMM: BM=128, BK=64, double-buffered, issue-early ----
// C (fp32 K-split partials at slab z) = adj[M][K] @ (BT[N][K])^T
template<int BN, int THREADS, int WM, int WN>
__global__ __launch_bounds__(THREADS, 4) void big_gemm_kernel(
    const float* __restrict__ A, const unsigned short* __restrict__ BT,
    float* __restrict__ C, int M, int N, int K) {
    constexpr int BM = 128, BK = 64, LDW = 72;
    constexpr int MF = BM / WM / 16, NF = BN / WN / 16;
    constexpr int ACH = (BM * BK / 4) / THREADS;   // float4 chunks of A per thread
    constexpr int BCH = (BN * BK / 8) / THREADS;   // us8 chunks of B per thread
    __shared__ alignas(16) unsigned short sA[2][BM * LDW];
    __shared__ alignas(16) unsigned short sB[2][BN * LDW];
    const int t = threadIdx.x, w = t >> 6, l = t & 63;
    const int wr = w / WN, wc = w % WN;
    const int m0 = blockIdx.x * BM;
    const int klen = K / gridDim.z, kbeg = blockIdx.z * klen;
    const int NT = klen / BK;
    float* Cp = C + (size_t)blockIdx.z * M * N;

    float4 ar[ACH];
    us8 br[BCH];

    auto LOAD = [&](int kc) {
#pragma unroll
        for (int p = 0; p < ACH; ++p) {
            int flat = p * THREADS + t, row = flat >> 4, c4 = flat & 15;
            ar[p] = *(const float4*)&A[(size_t)(m0 + row) * K + kc + c4 * 4];
        }
#pragma unroll
        for (int p = 0; p < BCH; ++p) {
            int flat = p * THREADS + t, row = flat >> 3, c8 = flat & 7;
            br[p] = *(const us8*)&BT[(size_t)row * K + kc + c8 * 8];
        }
    };
    auto WRITE = [&](int buf) {
#pragma unroll
        for (int p = 0; p < ACH; ++p) {
            int flat = p * THREADS + t, row = flat >> 4, c4 = flat & 15;
            float4 v = ar[p];
            *(ushort4*)&sA[buf][row * LDW + c4 * 4] =
                make_ushort4(f2bf(v.x), f2bf(v.y), f2bf(v.z), f2bf(v.w));
        }
#pragma unroll
        for (int p = 0; p < BCH; ++p) {
            int flat = p * THREADS + t, row = flat >> 3, c8 = flat & 7;
            *(us8*)&sB[buf][row * LDW + c8 * 8] = br[p];
        }
    };

    f32x4 acc[MF][NF] = {};
    LOAD(kbeg);
    WRITE(0);
    __syncthreads();
    int cur = 0;
    for (int tt = 0; tt < NT; ++tt) {
        if (tt + 1 < NT) LOAD(kbeg + (tt + 1) * BK);   // issue-early: in flight across compute
#pragma unroll
        for (int kk = 0; kk < BK; kk += 32) {
            bf16x8 av[MF], bv[NF];
#pragma unroll
            for (int m = 0; m < MF; ++m)
                av[m] = *(const bf16x8*)&sA[cur][(wr * (BM / WM) + m * 16 + (l & 15)) * LDW + kk + (l >> 4) * 8];
#pragma unroll
            for (int n = 0; n < NF; ++n)
                bv[n] = *(const bf16x8*)&sB[cur][(wc * (BN / WN) + n * 16 + (l & 15)) * LDW + kk + (l >> 4) * 8];
#pragma unroll
            for (int m = 0; m < MF; ++m)
#pragma unroll
                for (int n = 0; n < NF; ++n)
                    acc[m][n] = __builtin_amdgcn_mfma_f32_16x16x32_bf16(av[m], bv[n], acc[m][n], 0, 0, 0);
        }
        if (tt + 1 < NT) {
            WRITE(cur ^ 1);      // buf^1 is not being read: no pre-write barrier needed
            __syncthreads();
            cur ^= 1;
        }
    }
#pragma unroll
    for (int m = 0; m < MF; ++m)
#pragma unroll
        for (int n = 0; n < NF; ++n) {
            const int col = wc * (BN / WN) + n * 16 + (l & 15);
            const int rb = m0 + wr * (BM / WM) + m * 16 + ((l >> 4) << 2);
#pragma unroll
            for (int j = 0; j < 4; ++j)
                Cp[(size_t)(rb + j) * N + col] = acc[m][n][j];
        }
}

// ---- head: reduce 8 fp32 partial slabs of o[8192][64], then log_softmax rows ----
__global__ __launch_bounds__(256) void head2_kernel(
    const float* __restrict__ p, float* __restrict__ out, int M) {
    const int t = threadIdx.x, w = t >> 6, l = t & 63;
    const size_t stride = (size_t)M * 64;
#pragma unroll
    for (int rr = 0; rr < 4; ++rr) {
        int i = blockIdx.x * 16 + w * 4 + rr;
        size_t off = (size_t)i * 64 + l;
        float v = 0.f;
#pragma unroll
        for (int s = 0; s < 8; ++s) v += p[s * stride + off];
        float mx = v;
#pragma unroll
        for (int o = 32; o; o >>= 1) mx = fmaxf(mx, __shfl_xor(mx, o));
        float d0 = v - mx;
        float e = __expf(d0);
#pragma unroll
        for (int o = 32; o; o >>= 1) e += __shfl_xor(e, o);
        out[off] = d0 - __logf(e);
    }
}

extern "C" void kernel_launch(void* const* d_in, const int* in_sizes, int n_in,
                              void* d_out, int out_size, void* d_ws, size_t ws_size,
                              hipStream_t stream) {
    const float* adj = (const float*)d_in[0];
    const float* x   = (const float*)d_in[1];
    const float* W1  = (const float*)d_in[2];
    const float* W2  = (const float*)d_in[3];
    float* out = (float*)d_out;

    const int M = 8192, K = 8192;
    char* ws = (char*)d_ws;
    // ws layout (~55.8 MB; ws_size ~1 GB):
    float*          pbuf1 = (float*)ws;                        // 32 MB: 4 slabs t1 partials [8192][256]
    float*          pbuf2 = (float*)(ws + 33554432);           // 16 MB: 8 slabs o partials  [8192][64]
    unsigned short* zT    = (unsigned short*)(ws + 50331648);  //  4 MB: z^T  bf16 [256][8192]
    unsigned short* hwT   = (unsigned short*)(ws + 54525952);  //  1 MB: hw^T bf16 [64][8192]
    unsigned short* W1T   = (unsigned short*)(ws + 55574528);  // 128 KB
    unsigned short* W2T   = (unsigned short*)(ws + 55705600);  // 32 KB

    transpose_cast_kernel<<<dim3(4, 4), 256, 0, stream>>>(W1, W1T, 256, 256);
    transpose_cast_kernel<<<dim3(4, 1), 256, 0, stream>>>(W2, W2T, 256, 64);
    // z^T = (x @ W1)^T, bf16
    gemm_kernel<256, 1, 4, 1, true, unsigned short>
        <<<dim3(M / 64, 1, 1), 256, 0, stream>>>(x, W1T, zT, M, 256, 256, 0);
    // t1 partials = adj @ z  (K-split 4; 256 blocks = 1/CU, 16 waves)
    big_gemm_kernel<256, 1024, 4, 4>
        <<<dim3(M / 128, 1, 4), 1024, 0, stream>>>(adj, zT, pbuf1, M, 256, K);
    // hw^T = (relu(sum of 4 t1 slabs) @ W2)^T, bf16
    gemm_kernel<64, 2, 2, 2, true, unsigned short>
        <<<dim3(M / 64, 1, 1), 256, 0, stream>>>(pbuf1, W2T, hwT, M, 64, 256, (long)M * 256);
    // o partials = adj @ hw  (K-split 8; 512 blocks = 2/CU)
    big_gemm_kernel<64, 512, 4, 2>
        <<<dim3(M / 128, 1, 8), 512, 0, stream>>>(adj, hwT, pbuf2, M, 64, K);
    head2_kernel<<<dim3(M / 16), 256, 0, stream>>>(pbuf2, out, M);
}